// Round 2
// baseline (591.469 us; speedup 1.0000x reference)
//
#include <hip/hip_runtime.h>

#define N_NODES 100000
#define N_EDGES 3200000
#define N_GRAPHS 1000
#define NLAYER 4
#define NB 782           // coarse buckets: dst>>7, 782*128 = 100096 >= N_NODES
#define BBITS 7
#define EPB2 2048        // edges per block in scatter pass
#define G1 1563          // 1563*2048 >= N_EDGES
#define GH 782           // hist blocks: 782*4096 >= N_EDGES
#define PCAP 6144        // bucket_sort perm capacity (mean 4096, sd ~64)

typedef __attribute__((ext_vector_type(8))) short bf16x8;
typedef __attribute__((ext_vector_type(4))) float f32x4;

// round-to-nearest-even f32 -> bf16 (finite inputs)
static __device__ __forceinline__ unsigned f2bf(float f) {
  unsigned u = __float_as_uint(f);
  return (u + 0x7fffu + ((u >> 16) & 1u)) >> 16;
}
static __device__ __forceinline__ float bf2f_lo(unsigned u) {
  return __uint_as_float(u << 16);
}
static __device__ __forceinline__ float bf2f_hi(unsigned u) {
  return __uint_as_float(u & 0xffff0000u);
}

// ---------------------------------------------------------------------------
// graph-capture-safe zeroing (replaces hipMemsetAsync)
__global__ __launch_bounds__(256) void zero_kernel(int* __restrict__ p, int n)
{
  int i = blockIdx.x * 256 + threadIdx.x;
  if (i < n) p[i] = 0;
}

// ---------------------------------------------------------------------------
// h_bf[v][c] = bf16(sum_k x[v][k]*emb_w[k][c] + emb_b[c])
__global__ __launch_bounds__(256) void embed_kernel(
    const float* __restrict__ x, const float* __restrict__ emb_w,
    const float* __restrict__ emb_b, unsigned short* __restrict__ h_bf)
{
  int t = blockIdx.x * 256 + threadIdx.x;
  if (t >= N_NODES * 64) return;
  int c = t & 63, v = t >> 6;
  float4 xv = ((const float4*)x)[v];
  float acc = emb_b[c];
  acc = fmaf(xv.x, emb_w[0 * 64 + c], acc);
  acc = fmaf(xv.y, emb_w[1 * 64 + c], acc);
  acc = fmaf(xv.z, emb_w[2 * 64 + c], acc);
  acc = fmaf(xv.w, emb_w[3 * 64 + c], acc);
  h_bf[t] = (unsigned short)f2bf(acc);
}

// ---------------------------------------------------------------------------
// A: per-block LDS histogram of coarse bucket (dst>>7) -> global totals.
__global__ __launch_bounds__(256) void hist1_kernel(
    const int* __restrict__ ei, int* __restrict__ tots)
{
  __shared__ unsigned hist[NB];
  for (int i = threadIdx.x; i < NB; i += 256) hist[i] = 0;
  __syncthreads();
  int base = blockIdx.x * 4096;
#pragma unroll
  for (int i = 0; i < 16; ++i) {
    int e = base + i * 256 + threadIdx.x;
    if (e < N_EDGES) atomicAdd(&hist[((unsigned)ei[N_EDGES + e]) >> BBITS], 1u);
  }
  __syncthreads();
  for (int i = threadIdx.x; i < NB; i += 256) {
    unsigned c = hist[i];
    if (c) atomicAdd(&tots[i], (int)c);
  }
}

// B: exclusive scan of bucket totals -> bb[0..NB]; init gcur = bb.
__global__ __launch_bounds__(1024) void scan1_kernel(
    const int* __restrict__ tots, int* __restrict__ bb, int* __restrict__ gcur)
{
  __shared__ int s[1024];
  int t = threadIdx.x;
  int x = (t < NB) ? tots[t] : 0;
  s[t] = x;
  __syncthreads();
  for (int off = 1; off < 1024; off <<= 1) {
    int y = (t >= off) ? s[t - off] : 0;
    __syncthreads();
    s[t] += y;
    __syncthreads();
  }
  if (t < NB) {
    int ex = s[t] - x;
    bb[t] = ex;
    gcur[t] = ex;
  }
  if (t == 0) bb[NB] = N_EDGES;
}

// C: scatter edges into coarse buckets. Per-block ranges claimed with ONE
// global atomicAdd per (block,bucket); order within a bucket is arbitrary
// (only perturbs fp32 sum rounding). LDS-staged for coalesced writes.
// tmp record: x = src | ((dst&127)<<17), y = ew bits (exact f32)
__global__ __launch_bounds__(256) void bscatter2_kernel(
    const int* __restrict__ ei, const float* __restrict__ ea,
    int* __restrict__ gcur, int2* __restrict__ tmp)
{
  __shared__ unsigned hist[NB];   // histogram, then local cursor after scan
  __shared__ int dif[NB];         // globalbase - local_exclusive
  __shared__ int2 stage[EPB2];    // 16 KB
  __shared__ unsigned short bid[EPB2];  // 4 KB
  __shared__ int sbuf[256];
  __shared__ int carry;
  int tid = threadIdx.x;
  int base = blockIdx.x * EPB2;

  for (int i = tid; i < NB; i += 256) hist[i] = 0;
  if (tid == 0) carry = 0;
  __syncthreads();

#pragma unroll
  for (int i = 0; i < 8; ++i) {
    int e = base + i * 256 + tid;
    if (e < N_EDGES) atomicAdd(&hist[((unsigned)ei[N_EDGES + e]) >> BBITS], 1u);
  }
  __syncthreads();

  // claim global ranges, one atomic per nonzero bucket
  for (int b = tid; b < NB; b += 256) {
    int c = (int)hist[b];
    dif[b] = c ? atomicAdd(&gcur[b], c) : 0;
  }
  __syncthreads();

  // local exclusive scan of hist; hist becomes local cursor; dif -= excl
  for (int c0 = 0; c0 < NB; c0 += 256) {
    int g = c0 + tid;
    int v = (g < NB) ? (int)hist[g] : 0;
    sbuf[tid] = v;
    __syncthreads();
    for (int off = 1; off < 256; off <<= 1) {
      int y = (tid >= off) ? sbuf[tid - off] : 0;
      __syncthreads();
      sbuf[tid] += y;
      __syncthreads();
    }
    if (g < NB) {
      int ex = carry + sbuf[tid] - v;
      hist[g] = (unsigned)ex;   // local cursor
      dif[g] -= ex;             // gpos = dif[bkt] + local_pos
    }
    __syncthreads();
    if (tid == 0) carry += sbuf[255];
    __syncthreads();
  }

#pragma unroll
  for (int i = 0; i < 8; ++i) {
    int e = base + i * 256 + tid;
    if (e < N_EDGES) {
      int d = ei[N_EDGES + e];
      unsigned bkt = ((unsigned)d) >> BBITS;
      unsigned lp = atomicAdd(&hist[bkt], 1u);
      stage[lp] = make_int2(ei[e] | ((d & 127) << 17), __float_as_int(ea[e]));
      bid[lp] = (unsigned short)bkt;
    }
  }
  __syncthreads();

  int nE = min(EPB2, N_EDGES - base);
  for (int i = tid; i < nE; i += 256) {
    int bkt = (int)bid[i];
    tmp[dif[bkt] + i] = stage[i];
  }
}

// D: one block per bucket: 128-bin LDS counting sort (u16 permutation) ->
// contiguous streaming csr write (u32/edge: src 17b | ew*2^15 15b);
// emits row_off and fp32 degw.
__global__ __launch_bounds__(256) void bucket_sort2_kernel(
    const int* __restrict__ bb, const int2* __restrict__ tmp,
    unsigned* __restrict__ csr, int* __restrict__ row_off, float* __restrict__ degw)
{
  int j = blockIdx.x;
  int b0 = bb[j], b1 = bb[j + 1];
  int nE = b1 - b0;
  __shared__ unsigned hist[128];
  __shared__ float dws[128];
  __shared__ int scanbuf[256];
  __shared__ unsigned cur[128];
  __shared__ unsigned short perm[PCAP];  // 12 KB
  int t = threadIdx.x;
  if (t < 128) { hist[t] = 0; dws[t] = 0.f; }
  __syncthreads();
  for (int i = t; i < nE; i += 256) {
    int2 r = tmp[b0 + i];
    int bin = ((unsigned)r.x) >> 17;
    atomicAdd(&hist[bin], 1u);
    atomicAdd(&dws[bin], __int_as_float(r.y));
  }
  __syncthreads();
  int v = (t < 128) ? (int)hist[t] : 0;
  scanbuf[t] = v;
  __syncthreads();
  for (int off = 1; off < 256; off <<= 1) {
    int y = (t >= off) ? scanbuf[t - off] : 0;
    __syncthreads();
    scanbuf[t] += y;
    __syncthreads();
  }
  int myexcl = scanbuf[t] - v;
  if (t < 128) {
    cur[t] = (unsigned)myexcl;
    int vnode = (j << BBITS) + t;
    if (vnode < N_NODES) {
      row_off[vnode] = b0 + myexcl;
      degw[vnode] = dws[t];
    }
  }
  if (j == NB - 1 && t == 0) row_off[N_NODES] = N_EDGES;
  __syncthreads();

  if (nE <= PCAP) {
    for (int i = t; i < nE; i += 256) {
      int2 r = tmp[b0 + i];
      int bin = ((unsigned)r.x) >> 17;
      unsigned p = atomicAdd(&cur[bin], 1u);
      perm[p] = (unsigned short)i;
    }
    __syncthreads();
    for (int q = t; q < nE; q += 256) {
      int2 r = tmp[b0 + (int)perm[q]];
      unsigned q15 = (unsigned)(__int_as_float(r.y) * 32768.0f);  // ew in [0,1)
      csr[b0 + q] = ((unsigned)r.x & 0x1FFFFu) | (q15 << 17);
    }
  } else {
    for (int i = t; i < nE; i += 256) {
      int2 r = tmp[b0 + i];
      int bin = ((unsigned)r.x) >> 17;
      unsigned p = atomicAdd(&cur[bin], 1u);
      unsigned q15 = (unsigned)(__int_as_float(r.y) * 32768.0f);
      csr[b0 + (int)p] = ((unsigned)r.x & 0x1FFFFu) | (q15 << 17);
    }
  }
}

// ---------------------------------------------------------------------------
// Degree-ordered node permutation: equalizes per-subgroup trip counts in agg
// so the 4 nodes in a wave have (near-)equal degree and no issue slot is
// wasted on masked lanes.
__global__ __launch_bounds__(256) void dhist_kernel(
    const int* __restrict__ row_off, int* __restrict__ dhist)
{
  __shared__ unsigned h[256];
  int t = threadIdx.x;
  h[t] = 0;
  __syncthreads();
  int v0 = (blockIdx.x * 256 + t) * 4;
#pragma unroll
  for (int k = 0; k < 4; ++k) {
    int v = v0 + k;
    if (v < N_NODES) {
      int d = row_off[v + 1] - row_off[v];
      atomicAdd(&h[min(d, 255)], 1u);
    }
  }
  __syncthreads();
  unsigned c = h[t];
  if (c) atomicAdd(&dhist[t], (int)c);
}

__global__ __launch_bounds__(256) void dscan_kernel(
    const int* __restrict__ dhist, int* __restrict__ dcur)
{
  __shared__ int s[256];
  int t = threadIdx.x;
  int v = dhist[t];
  s[t] = v;
  __syncthreads();
  for (int off = 1; off < 256; off <<= 1) {
    int y = (t >= off) ? s[t - off] : 0;
    __syncthreads();
    s[t] += y;
    __syncthreads();
  }
  dcur[t] = s[t] - v;  // exclusive
}

__global__ __launch_bounds__(256) void dperm_kernel(
    const int* __restrict__ row_off, int* __restrict__ dcur,
    int* __restrict__ nodeperm)
{
  __shared__ unsigned h[256];
  __shared__ unsigned lcur[256];
  int t = threadIdx.x;
  h[t] = 0;
  __syncthreads();
  int v0 = (blockIdx.x * 256 + t) * 4;
  int dloc[4];
#pragma unroll
  for (int k = 0; k < 4; ++k) {
    int v = v0 + k;
    dloc[k] = -1;
    if (v < N_NODES) {
      int d = min(row_off[v + 1] - row_off[v], 255);
      dloc[k] = d;
      atomicAdd(&h[d], 1u);
    }
  }
  __syncthreads();
  unsigned c = h[t];
  unsigned gb = c ? (unsigned)atomicAdd(&dcur[t], (int)c) : 0u;
  lcur[t] = gb;
  __syncthreads();
#pragma unroll
  for (int k = 0; k < 4; ++k) {
    if (dloc[k] >= 0) {
      unsigned p = atomicAdd(&lcur[dloc[k]], 1u);
      nodeperm[p] = v0 + k;
    }
  }
}

// ---------------------------------------------------------------------------
// One-time weight swizzle: all 4 layers' W2/W3/W1 into MFMA B-fragment
// layout in GLOBAL memory (4 x 24 KB). Same verified mapping as before.
// grid = NLAYER blocks x 256 threads.
__global__ __launch_bounds__(256) void wswz_kernel(
    const float* __restrict__ cw1, const float* __restrict__ cw2,
    const float* __restrict__ cw3, unsigned* __restrict__ wswz)
{
  int l = blockIdx.x;
  const float* w1 = cw1 + l * 4096;
  const float* w2 = cw2 + l * 4096;
  const float* w3 = cw3 + l * 4096;
  unsigned* outp = wswz + l * 6144;
  int tid = threadIdx.x;
  int n = tid & 63;
  int gofs = tid >> 6;
  for (int it = 0; it < 24; ++it) {
    int g = it * 4 + gofs;         // 0..95
    int m = g >> 5;                // 0..2 (0=W2, 1=W3, 2=W1)
    int kp = g & 31;               // k-pair index
    int k = kp * 2;                // even k
    const float* W = (m == 0) ? w2 : (m == 1) ? w3 : w1;
    unsigned lo = f2bf(W[k * 64 + n]);
    unsigned hi = f2bf(W[(k + 1) * 64 + n]);
    int c = k >> 5;
    int kk = k & 31;
    int lane = ((kk >> 3) << 4) | (n & 15);
    int j2 = (kk & 7) >> 1;
    int t = n >> 4;
    outp[(((m * 2 + c) * 4 + t) << 8) | (lane << 2) | j2] = lo | (hi << 16);
  }
}

// ---------------------------------------------------------------------------
// MFMA matvec: one 16-node tile per wave, grid = 6250 waves (1563 blocks).
// No LDS, no barrier: B-fragments loaded directly from the pre-swizzled
// global wswz slice (24 KB, L1-resident; per-fragment load is lane*16B
// coalesced). A-frags from h_bf (verified layout).
//   a_bf  = bf16(h@W1 + b1)
//   cc_bf = bf16(b3 + h@W3 - deg_w*(h@W2))
__global__ __launch_bounds__(256) void matvec3_mfma_kernel(
    const unsigned short* __restrict__ h_bf,
    const unsigned* __restrict__ wz,   // this layer's 6144-word slice
    const float* __restrict__ b1, const float* __restrict__ b3,
    const float* __restrict__ degw,
    unsigned short* __restrict__ a_bf, unsigned short* __restrict__ cc_bf)
{
  int gw = (blockIdx.x * 256 + threadIdx.x) >> 6;  // global wave = tile index
  int lane = threadIdx.x & 63;
  int quad = lane >> 4;
  int col = lane & 15;
  int nb = gw * 16;  // node base of this wave's 16 rows
  if (nb >= N_NODES) return;  // wave-uniform exit

  int arow = nb + col;
  if (arow >= N_NODES) arow = N_NODES - 1;
  const bf16x8* ap = (const bf16x8*)(h_bf + (size_t)arow * 64 + quad * 8);
  bf16x8 af0 = ap[0];  // k = quad*8 + j
  bf16x8 af1 = ap[4];  // k = 32 + quad*8 + j

  float dwr[4];
#pragma unroll
  for (int r = 0; r < 4; ++r) {
    int row = nb + quad * 4 + r;
    dwr[r] = degw[row < N_NODES ? row : 0];
  }

#pragma unroll
  for (int t = 0; t < 4; ++t) {
    const bf16x8* b20 = (const bf16x8*)&wz[((0 * 4 + t) << 8) + lane * 4];
    const bf16x8* b21 = (const bf16x8*)&wz[((1 * 4 + t) << 8) + lane * 4];
    const bf16x8* b30 = (const bf16x8*)&wz[((2 * 4 + t) << 8) + lane * 4];
    const bf16x8* b31 = (const bf16x8*)&wz[((3 * 4 + t) << 8) + lane * 4];
    const bf16x8* b10 = (const bf16x8*)&wz[((4 * 4 + t) << 8) + lane * 4];
    const bf16x8* b11 = (const bf16x8*)&wz[((5 * 4 + t) << 8) + lane * 4];

    f32x4 z = {0.f, 0.f, 0.f, 0.f};
    f32x4 acc2 = __builtin_amdgcn_mfma_f32_16x16x32_bf16(af0, *b20, z, 0, 0, 0);
    acc2 = __builtin_amdgcn_mfma_f32_16x16x32_bf16(af1, *b21, acc2, 0, 0, 0);
    f32x4 cc;
#pragma unroll
    for (int r = 0; r < 4; ++r) cc[r] = -dwr[r] * acc2[r];
    cc = __builtin_amdgcn_mfma_f32_16x16x32_bf16(af0, *b30, cc, 0, 0, 0);
    cc = __builtin_amdgcn_mfma_f32_16x16x32_bf16(af1, *b31, cc, 0, 0, 0);
    float bb3 = b3[t * 16 + col];
#pragma unroll
    for (int r = 0; r < 4; ++r) {
      int row = nb + quad * 4 + r;
      if (row < N_NODES)
        cc_bf[(size_t)row * 64 + t * 16 + col] = (unsigned short)f2bf(cc[r] + bb3);
    }

    float bb1 = b1[t * 16 + col];
    f32x4 a1 = {bb1, bb1, bb1, bb1};
    a1 = __builtin_amdgcn_mfma_f32_16x16x32_bf16(af0, *b10, a1, 0, 0, 0);
    a1 = __builtin_amdgcn_mfma_f32_16x16x32_bf16(af1, *b11, a1, 0, 0, 0);
#pragma unroll
    for (int r = 0; r < 4; ++r) {
      int row = nb + quad * 4 + r;
      if (row < N_NODES)
        a_bf[(size_t)row * 64 + t * 16 + col] = (unsigned short)f2bf(a1[r]);
    }
  }
}

// ---------------------------------------------------------------------------
// h_new[v] = relu(cc[v] + sum_{e in CSR(v)} ew_e * a[src_e])
// 4 nodes/wave (degree-sorted via nodeperm), 16 lanes per node; exact
// per-subgroup trip counts. a/cc bf16; csr u32 (src|q15<<17).
// Writes h_bf always; fp32 h only when write_h != 0 (last layer, for head).
__global__ __launch_bounds__(256) void agg_kernel(
    const uint2* __restrict__ a2, const uint2* __restrict__ cc2,
    const int* __restrict__ row_off, const unsigned* __restrict__ csr,
    const int* __restrict__ nodeperm,
    float4* __restrict__ h4, unsigned short* __restrict__ h_bf, int write_h)
{
  int wave = (blockIdx.x * 256 + threadIdx.x) >> 6;
  int lane = threadIdx.x & 63;
  int sg = lane >> 4;
  int li = lane & 15;
  int lsel = (lane & 48) << 2;  // sg*64 : byte lane-address base for bpermute
  int vslot = wave * 4 + sg;
  bool valid = vslot < N_NODES;
  int v = nodeperm[valid ? vslot : N_NODES - 1];
  int base = row_off[v];
  int ecnt = valid ? (row_off[v + 1] - base) : 0;

  float4 acc = make_float4(0.f, 0.f, 0.f, 0.f);
  if (valid) {
    uint2 cu = cc2[(size_t)v * 16 + li];
    acc.x = bf2f_lo(cu.x);
    acc.y = bf2f_hi(cu.x);
    acc.z = bf2f_lo(cu.y);
    acc.w = bf2f_hi(cu.y);
  }
  const uint2* ap = a2 + li;

  int full = ecnt & ~15;
  int c0 = 0;
  for (; c0 < full; c0 += 16) {
    int er = (int)csr[base + c0 + li];  // always in-row: c0+15 < ecnt
#pragma unroll
    for (int j = 0; j < 16; ++j) {
      unsigned r = (unsigned)__builtin_amdgcn_ds_bpermute(lsel | (j << 2), er);
      int s = (int)(r & 0x1FFFFu);
      float w = (float)(r >> 17) * (1.0f / 32768.0f);
      uint2 u = ap[(size_t)s * 16];
      acc.x = fmaf(w, bf2f_lo(u.x), acc.x);
      acc.y = fmaf(w, bf2f_hi(u.x), acc.y);
      acc.z = fmaf(w, bf2f_lo(u.y), acc.z);
      acc.w = fmaf(w, bf2f_hi(u.y), acc.w);
    }
  }
  int rem = ecnt - full;
  if (rem > 0) {
    int idx = c0 + li;
    int er = (idx < ecnt) ? (int)csr[base + idx] : 0;
    for (int j = 0; j < rem; ++j) {
      unsigned r = (unsigned)__builtin_amdgcn_ds_bpermute(lsel | (j << 2), er);
      int s = (int)(r & 0x1FFFFu);
      float w = (float)(r >> 17) * (1.0f / 32768.0f);
      uint2 u = ap[(size_t)s * 16];
      acc.x = fmaf(w, bf2f_lo(u.x), acc.x);
      acc.y = fmaf(w, bf2f_hi(u.x), acc.y);
      acc.z = fmaf(w, bf2f_lo(u.y), acc.z);
      acc.w = fmaf(w, bf2f_hi(u.y), acc.w);
    }
  }
  if (valid) {
    acc.x = fmaxf(acc.x, 0.f);
    acc.y = fmaxf(acc.y, 0.f);
    acc.z = fmaxf(acc.z, 0.f);
    acc.w = fmaxf(acc.w, 0.f);
    if (write_h) h4[(size_t)v * 16 + li] = acc;
    uint2 p;
    p.x = f2bf(acc.x) | (f2bf(acc.y) << 16);
    p.y = f2bf(acc.z) | (f2bf(acc.w) << 16);
    ((uint2*)h_bf)[(size_t)v * 16 + li] = p;
  }
}

// ---------------------------------------------------------------------------
// fused mean-pool (sorted batch, binary search) + lin1+relu + lin2, wave/graph
__global__ __launch_bounds__(256) void head_kernel(
    const float* __restrict__ h, const int* __restrict__ batch,
    const float* __restrict__ l1w, const float* __restrict__ l1b,
    const float* __restrict__ l2w, const float* __restrict__ l2b,
    float* __restrict__ out)
{
  int g = (blockIdx.x * 256 + threadIdx.x) >> 6;
  int lane = threadIdx.x & 63;
  if (g >= N_GRAPHS) return;
  int lo = 0, hi = N_NODES;
  while (lo < hi) { int mid = (lo + hi) >> 1; if (batch[mid] < g) lo = mid + 1; else hi = mid; }
  int start = lo;
  hi = N_NODES;
  while (lo < hi) { int mid = (lo + hi) >> 1; if (batch[mid] < g + 1) lo = mid + 1; else hi = mid; }
  int end = lo;

  float sum = 0.f;
  for (int v = start; v < end; ++v) sum += h[(size_t)v * 64 + lane];
  float cntf = (float)(end - start);
  float gx = sum / fmaxf(cntf, 1.f);

  float acc = l1b[lane];
  for (int k = 0; k < 64; ++k) {
    float gxk = __shfl(gx, k);
    acc = fmaf(gxk, l1w[k * 64 + lane], acc);
  }
  float t = fmaxf(acc, 0.f);
  float p0 = t * l2w[lane * 3 + 0];
  float p1 = t * l2w[lane * 3 + 1];
  float p2 = t * l2w[lane * 3 + 2];
  for (int off = 32; off > 0; off >>= 1) {
    p0 += __shfl_down(p0, off);
    p1 += __shfl_down(p1, off);
    p2 += __shfl_down(p2, off);
  }
  if (lane == 0) {
    out[g * 3 + 0] = p0 + l2b[0];
    out[g * 3 + 1] = p1 + l2b[1];
    out[g * 3 + 2] = p2 + l2b[2];
  }
}

// ---------------------------------------------------------------------------
extern "C" void kernel_launch(void* const* d_in, const int* in_sizes, int n_in,
                              void* d_out, int out_size, void* d_ws, size_t ws_size,
                              hipStream_t stream)
{
  (void)in_sizes; (void)n_in; (void)out_size; (void)ws_size;
  const float* x     = (const float*)d_in[0];
  const int*   ei    = (const int*)d_in[1];
  const float* ea    = (const float*)d_in[2];
  const int*   batch = (const int*)d_in[3];
  const float* emb_w = (const float*)d_in[4];
  const float* emb_b = (const float*)d_in[5];
  const float* cw1   = (const float*)d_in[6];
  const float* cb1   = (const float*)d_in[7];
  const float* cw2   = (const float*)d_in[8];
  const float* cw3   = (const float*)d_in[9];
  const float* cb3   = (const float*)d_in[10];
  const float* l1w   = (const float*)d_in[11];
  const float* l1b   = (const float*)d_in[12];
  const float* l2w   = (const float*)d_in[13];
  const float* l2b   = (const float*)d_in[14];
  float* out = (float*)d_out;

  char* wsb = (char*)d_ws;
  size_t off = 0;
  auto alloc = [&](size_t bytes) {
    char* p = wsb + off;
    off = (off + bytes + 255) & ~(size_t)255;
    return p;
  };
  float* h       = (float*)alloc(sizeof(float) * (size_t)N_NODES * 64);    // 25.6 MB
  unsigned short* h_bf = (unsigned short*)alloc(sizeof(short) * (size_t)N_NODES * 64);
  unsigned short* a_bf = (unsigned short*)alloc(sizeof(short) * (size_t)N_NODES * 64);
  unsigned short* cc_bf = (unsigned short*)alloc(sizeof(short) * (size_t)N_NODES * 64);
  unsigned* csr  = (unsigned*)alloc(sizeof(unsigned) * (size_t)N_EDGES);   // 12.8 MB
  int*   row_off = (int*)alloc(sizeof(int) * (N_NODES + 1));
  float* degw    = (float*)alloc(sizeof(float) * N_NODES);
  int*   nodeperm= (int*)alloc(sizeof(int) * N_NODES);
  int*   tots    = (int*)alloc(sizeof(int) * NB);
  int*   dhist_g = (int*)alloc(sizeof(int) * 256);
  int*   bb      = (int*)alloc(sizeof(int) * (NB + 1));
  int*   gcur    = (int*)alloc(sizeof(int) * NB);
  int*   dcur    = (int*)alloc(sizeof(int) * 256);
  unsigned* wswz = (unsigned*)alloc(sizeof(unsigned) * NLAYER * 6144);  // 96 KB
  // tmp (25.6 MB int2) aliases h: h fp32 is only written by the LAST agg,
  // long after bucket_sort consumed tmp.
  int2* tmp = (int2*)h;

  // zero tots + dhist (graph-capture-safe; no hipMemsetAsync)
  zero_kernel<<<(NB + 255) / 256, 256, 0, stream>>>(tots, NB);
  zero_kernel<<<1, 256, 0, stream>>>(dhist_g, 256);

  embed_kernel<<<(N_NODES * 64 + 255) / 256, 256, 0, stream>>>(x, emb_w, emb_b, h_bf);
  wswz_kernel<<<NLAYER, 256, 0, stream>>>(cw1, cw2, cw3, wswz);
  hist1_kernel<<<GH, 256, 0, stream>>>(ei, tots);
  scan1_kernel<<<1, 1024, 0, stream>>>(tots, bb, gcur);
  bscatter2_kernel<<<G1, 256, 0, stream>>>(ei, ea, gcur, tmp);
  bucket_sort2_kernel<<<NB, 256, 0, stream>>>(bb, tmp, csr, row_off, degw);
  dhist_kernel<<<98, 256, 0, stream>>>(row_off, dhist_g);
  dscan_kernel<<<1, 256, 0, stream>>>(dhist_g, dcur);
  dperm_kernel<<<98, 256, 0, stream>>>(row_off, dcur, nodeperm);

  int agg_blocks = (N_NODES + 15) / 16;   // 4 nodes/wave, 4 waves/block
  int mv_blocks = (N_NODES / 16 + 3) / 4 + 1;  // 6250 tiles, 4 waves/block -> 1563
  for (int l = 0; l < NLAYER; ++l) {
    matvec3_mfma_kernel<<<mv_blocks, 256, 0, stream>>>(
        h_bf, wswz + l * 6144, cb1 + l * 64, cb3 + l * 64, degw, a_bf, cc_bf);
    agg_kernel<<<agg_blocks, 256, 0, stream>>>(
        (const uint2*)a_bf, (const uint2*)cc_bf, row_off, csr, nodeperm, (float4*)h,
        h_bf, (l == NLAYER - 1) ? 1 : 0);
  }

  head_kernel<<<(N_GRAPHS * 64 + 255) / 256, 256, 0, stream>>>(
      h, batch, l1w, l1b, l2w, l2b, out);
}